// Round 5
// baseline (213.954 us; speedup 1.0000x reference)
//
#include <hip/hip_runtime.h>

// ---------------- problem constants ----------------
#define BATCH   8
#define LSEQ    1048576          // 1<<20
#define KCONV   500
#define TWIN    2097             // (L-K)/K + 1
#define MROWS   16776            // BATCH*TWIN
#define KDIM    4000             // KCONV * C_IN
#define NDIM    256              // 2 * C_OUT
#define COUT    128
#define VOCAB   257
#define VOCABP  256              // padding row of emb (zeros)

#define BMR     32               // m-rows per block (2 x 16)  [was 80]
#define NTILE   525              // ceil(MROWS/32): ~2 blocks/CU co-resident
#define SLABP   20               // positions per slab = 160 k = 5 BK32 iters
#define NSLAB   25
#define NG      125              // total BK32 iterations
#define PLANE   (NDIM * 32)      // 8192 shorts per g-plane of Wtf
#define AROWSH  168              // padded shorts per A-slab row (160 + 8)
#define STAGEN  (BMR * SLABP)    // 640 gathers per slab

// ---------------- ws layout (bytes) ----------------
#define WTF_OFF   0ull
#define WTF_BYTES ((size_t)NG * PLANE * 2)                  // 2,048,000
#define POOL_OFF  (WTF_OFF + WTF_BYTES)                     // 1024 floats
#define CNT_OFF   (POOL_OFF + 4096)                         // 1 int

typedef __attribute__((ext_vector_type(8))) __bf16 bf16x8;
typedef __attribute__((ext_vector_type(4))) float  floatx4;

__device__ inline unsigned short f2bf(float f) {
    union { float f; unsigned u; } c; c.f = f;
    return (unsigned short)((c.u + 0x7FFFu + ((c.u >> 16) & 1u)) >> 16);
}
__device__ inline unsigned pack2(float lo, float hi) {
    return (unsigned)f2bf(lo) | ((unsigned)f2bf(hi) << 16);
}

// barrier that waits ONLY for LDS ops — leaves global (B/x prefetch) loads in flight
#define LDS_BARRIER() asm volatile("s_waitcnt lgkmcnt(0)\n\ts_barrier" ::: "memory")

// ---------------- kernel 1: frag-major weights + zero pool/counter ----------------
// Wtf[g][n][kk] = w_n[e=(g*32+kk)&7][p=(g*32+kk)>>3]
__global__ __launch_bounds__(256) void wprep_kernel(const float* __restrict__ w1,
                                                    const float* __restrict__ w2,
                                                    unsigned short* __restrict__ Wtf,
                                                    float* __restrict__ pool,
                                                    int* __restrict__ cnt) {
    const int n   = blockIdx.x;                        // 0..255
    const int tid = threadIdx.x;
    __shared__ float tile[KDIM];                       // 16 KB
    const float* src = (n < COUT) ? (w1 + (size_t)n * KDIM)
                                  : (w2 + (size_t)(n - COUT) * KDIM);
    for (int i = tid; i < KDIM; i += 256) tile[i] = src[i];
    __syncthreads();
    for (int i = tid; i < KDIM; i += 256) {
        int g = i >> 5, kk = i & 31;
        Wtf[(size_t)g * PLANE + n * 32 + kk] = f2bf(tile[(i & 7) * KCONV + (i >> 3)]);
    }
    if (n == 0) {
        if (tid < 256) ((float4*)pool)[tid] = float4{0.f, 0.f, 0.f, 0.f}; // full 1024 floats
        if (tid == 0) *cnt = 0;
    }
}

// ---------------- kernel 2: fused embed + full-K GEMM + gate + max-pool + head ----------------
// OCCUPANCY RESTRUCTURE (round 5): BMR 80->32, grid 210->525. Previous grids
// gave 1 block/CU (8 waves = 2/SIMD, 46 CUs idle, OccupancyPercent ~14-16):
// every staging burst + barrier was fully exposed — no co-resident block to
// overlap with. Now LDS=26KB, VGPR~64 -> 4 blocks/CU schedulable; all 525
// blocks resident at once (2-3/CU, 16-24 waves/CU): one block's MFMA phase
// hides another's staging/barrier (m114 co-scheduling). Total gather/MFMA
// work is unchanged; per-CU LDS + L1-B traffic checked within pipe budgets.
// Per-block structure otherwise identical to the proven round-0 kernel:
// A: LDS emb-table gathers, slab double-buffered, compute-first ordering so
//    kt=0's af waits cover only its own ds_reads and staging drains into the
//    lgkm-only barrier. B: frag-major Wtf, depth-2 register prefetch (never
//    drained by LDS_BARRIER). x prefetched a full slab ahead on vmcnt.
// HEAD FUSION: no cache-maintenance fences (atomicMax is device-scope on
// CDNA): vmcnt(0) drain -> __syncthreads -> RELAXED agent fetch_add; winner
// reads pool with per-access agent-scope loads.
__global__ __launch_bounds__(512) void gemm_kernel(const int* __restrict__ x,
                                                   const float* __restrict__ emb,
                                                   const unsigned short* __restrict__ Wtf,
                                                   const float* __restrict__ b1,
                                                   const float* __restrict__ b2,
                                                   float* __restrict__ pool,
                                                   int* __restrict__ cnt,
                                                   const float* __restrict__ wd1,
                                                   const float* __restrict__ bd1,
                                                   const float* __restrict__ wd2,
                                                   const float* __restrict__ bd2,
                                                   float* __restrict__ out) {
    __shared__ unsigned short tableL[VOCAB * 8];       // 4112 B
    __shared__ unsigned short As[2][BMR * AROWSH];     // 2 x 10.5 KB

    const int tid  = threadIdx.x;
    const int lane = tid & 63;
    const int wv   = tid >> 6;                         // 0..7
    const int m0   = blockIdx.x * BMR;
    const int r16  = lane & 15;
    const int q    = lane >> 4;                        // 0..3

    // ---- build bf16 emb table in LDS ----
    if (tid < VOCAB) {
        const float4* er = (const float4*)(emb + tid * 8);
        float4 a = er[0], b = er[1];
        uint4 u;
        u.x = pack2(a.x, a.y); u.y = pack2(a.z, a.w);
        u.z = pack2(b.x, b.y); u.w = pack2(b.z, b.w);
        *(uint4*)(tableL + tid * 8) = u;
    }

    // ---- staging roles: thread handles idx = tid + 512*l (idx < 640) ----
    const int* xptr[2];
    int        loff[2];
    bool       sval[2];
#pragma unroll
    for (int l = 0; l < 2; ++l) {
        int idx = tid + 512 * l;
        sval[l] = (idx < STAGEN);
        int ic  = sval[l] ? idx : 0;
        int row = ic / SLABP;
        int pos = ic - row * SLABP;
        int am  = m0 + row;
        bool av = sval[l] && (am < MROWS);
        sval[l] = av;
        int amc = av ? am : 0;
        int b   = amc / TWIN;
        int t   = amc - b * TWIN;
        xptr[l] = x + ((size_t)b * LSEQ + (size_t)t * KCONV + pos);
        loff[l] = row * AROWSH + pos * 8;
    }

    // ---- compute role ----
    const int o = wv * 16 + r16;                       // 0..127
    const size_t boff0 = (size_t)o * 32 + q * 8;
    const size_t boff1 = (size_t)(o + 128) * 32 + q * 8;

    floatx4 acc[2][2];
#pragma unroll
    for (int i = 0; i < 2; ++i) { acc[i][0] = floatx4{0,0,0,0}; acc[i][1] = floatx4{0,0,0,0}; }

    // ---- x values for slab 0 ----
    int xv[2], xn[2];
#pragma unroll
    for (int l = 0; l < 2; ++l) xv[l] = sval[l] ? xptr[l][0] : VOCABP;
    __syncthreads();                                   // table visible

    // ---- stage slab 0 into buf 0 (unavoidably before first compute) ----
#pragma unroll
    for (int l = 0; l < 2; ++l) {
        if (l == 1 && tid >= STAGEN - 512) break;
        uint4 g = *(const uint4*)(tableL + xv[l] * 8);
        *(uint4*)((unsigned short*)As + loff[l]) = g;
    }
#pragma unroll
    for (int l = 0; l < 2; ++l) xv[l] = sval[l] ? xptr[l][SLABP] : VOCABP;
    LDS_BARRIER();

    // ---- B prefetch prologue: g=0,1 ----
    bf16x8 bc0[2], bc1[2], bc2[2] = {};
    bc0[0] = *(const bf16x8*)(Wtf + boff0);
    bc0[1] = *(const bf16x8*)(Wtf + boff1);
    bc1[0] = *(const bf16x8*)(Wtf + PLANE + boff0);
    bc1[1] = *(const bf16x8*)(Wtf + PLANE + boff1);

    int buf = 0;
    for (int s = 0; s < NSLAB; ++s) {
        // issue x loads for slab s+2 early (vmcnt; a full slab of cover)
        if (s + 2 < NSLAB) {
#pragma unroll
            for (int l = 0; l < 2; ++l)
                xn[l] = sval[l] ? xptr[l][(s + 2) * SLABP] : VOCABP;
        }

        // ---- 5 BK=32 iterations from As[buf]; B depth-2 register pipeline ----
        const unsigned short* Asb = (const unsigned short*)As + buf * (BMR * AROWSH);
#pragma unroll
        for (int kt = 0; kt < 5; ++kt) {
            const int g = s * 5 + kt;
            if (g + 2 < NG) {
                const unsigned short* Wp = Wtf + (size_t)(g + 2) * PLANE;
                bc2[0] = *(const bf16x8*)(Wp + boff0);
                bc2[1] = *(const bf16x8*)(Wp + boff1);
            }
            bf16x8 af[2];
#pragma unroll
            for (int i = 0; i < 2; ++i)
                af[i] = *(const bf16x8*)(Asb + (i * 16 + r16) * AROWSH + (kt * 4 + q) * 8);
#pragma unroll
            for (int i = 0; i < 2; ++i) {
                acc[i][0] = __builtin_amdgcn_mfma_f32_16x16x32_bf16(af[i], bc0[0], acc[i][0], 0, 0, 0);
                acc[i][1] = __builtin_amdgcn_mfma_f32_16x16x32_bf16(af[i], bc0[1], acc[i][1], 0, 0, 0);
            }
            bc0[0] = bc1[0]; bc0[1] = bc1[1];
            bc1[0] = bc2[0]; bc1[1] = bc2[1];
        }

        // ---- NOW stage slab s+1 into buf^1 (drains into the barrier) ----
        if (s + 1 < NSLAB) {
            unsigned short* d = (unsigned short*)As + (buf ^ 1) * (BMR * AROWSH);
#pragma unroll
            for (int l = 0; l < 2; ++l) {
                if (l == 1 && tid >= STAGEN - 512) break;
                uint4 g = *(const uint4*)(tableL + xv[l] * 8);
                *(uint4*)(d + loff[l]) = g;
            }
        }
#pragma unroll
        for (int l = 0; l < 2; ++l) xv[l] = xn[l];
        LDS_BARRIER();
        buf ^= 1;
    }

    // ---- epilogue: gate + per-batch max in registers, atomicMax flush ----
    // C/D layout: col = lane&15 (n), row = q*4 + reg (m).
    const float b1v = b1[o], b2v = b2[o];
    float cur = 0.0f;
    int curb  = (m0 + q * 4) / TWIN;
#pragma unroll
    for (int i = 0; i < 2; ++i) {
#pragma unroll
        for (int rg = 0; rg < 4; ++rg) {
            const int row = m0 + i * 16 + q * 4 + rg;
            if (row < MROWS) {
                const int bb = row / TWIN;
                if (bb != curb) {
                    atomicMax((int*)&pool[curb * COUT + o], __float_as_int(cur));
                    cur = 0.0f; curb = bb;
                }
                const float c1 = acc[i][0][rg] + b1v;
                const float c2 = acc[i][1][rg] + b2v;
                const float g  = fmaxf(c1, 0.0f) / (1.0f + __expf(-c2));
                cur = fmaxf(cur, g);
            }
        }
    }
    atomicMax((int*)&pool[curb * COUT + o], __float_as_int(cur));

    // ---- fused head: last block to finish does the dense layers ----
    // Drain this wave's device-scope atomics (completion at coherent point),
    // then barrier so ALL waves' atomics are drained, then relaxed counter.
    asm volatile("s_waitcnt vmcnt(0)" ::: "memory");
    __syncthreads();
    __shared__ int lastFlag;
    if (tid == 0) {
        int prev = __hip_atomic_fetch_add(cnt, 1, __ATOMIC_RELAXED, __HIP_MEMORY_SCOPE_AGENT);
        lastFlag = (prev == NTILE - 1) ? 1 : 0;
    }
    __syncthreads();
    if (!lastFlag) return;

    // reuse As as scratch: poolL[1024] + red[8][128]
    float* poolL = (float*)As;
    float* red   = poolL + BATCH * COUT;
    // agent-scope per-access loads: coherent view of the atomicMax results
    poolL[tid] = __int_as_float(
        __hip_atomic_load((int*)&pool[tid], __ATOMIC_RELAXED, __HIP_MEMORY_SCOPE_AGENT));
    poolL[tid + 512] = __int_as_float(
        __hip_atomic_load((int*)&pool[tid + 512], __ATOMIC_RELAXED, __HIP_MEMORY_SCOPE_AGENT));
    __syncthreads();

    if (tid < COUT) {
        const int j = tid;
        const float wj = wd2[j];
#pragma unroll
        for (int b = 0; b < BATCH; ++b) {
            float s = bd1[j];
            for (int i = 0; i < COUT; ++i) s += poolL[b * COUT + i] * wd1[j * COUT + i];
            red[b * COUT + j] = fmaxf(s, 0.0f) * wj;
        }
    }
    __syncthreads();
    if (tid < BATCH) {
        float s = 0.0f;
        for (int i = 0; i < COUT; ++i) s += red[tid * COUT + i];
        out[tid] = 1.0f / (1.0f + expf(-(s + bd2[0])));
    }
}

// ---------------- launch ----------------
extern "C" void kernel_launch(void* const* d_in, const int* in_sizes, int n_in,
                              void* d_out, int out_size, void* d_ws, size_t ws_size,
                              hipStream_t stream) {
    const int*   x   = (const int*)d_in[0];
    const float* emb = (const float*)d_in[1];
    const float* w1  = (const float*)d_in[2];
    const float* b1  = (const float*)d_in[3];
    const float* w2  = (const float*)d_in[4];
    const float* b2  = (const float*)d_in[5];
    const float* wd1 = (const float*)d_in[6];
    const float* bd1 = (const float*)d_in[7];
    const float* wd2 = (const float*)d_in[8];
    const float* bd2 = (const float*)d_in[9];
    float* out = (float*)d_out;

    unsigned short* Wtf  = (unsigned short*)((char*)d_ws + WTF_OFF);
    float*          pool = (float*)((char*)d_ws + POOL_OFF);
    int*            cnt  = (int*)((char*)d_ws + CNT_OFF);

    wprep_kernel<<<dim3(NDIM), dim3(256), 0, stream>>>(w1, w2, Wtf, pool, cnt);
    gemm_kernel<<<dim3(NTILE), dim3(512), 0, stream>>>(x, emb, Wtf, b1, b2, pool, cnt,
                                                       wd1, bd1, wd2, bd2, out);
}

// Round 6
// 169.710 us; speedup vs baseline: 1.2607x; 1.2607x over previous
//
#include <hip/hip_runtime.h>

// ---------------- problem constants ----------------
#define BATCH   8
#define LSEQ    1048576          // 1<<20
#define KCONV   500
#define TWIN    2097             // (L-K)/K + 1
#define MROWS   16776            // BATCH*TWIN
#define KDIM    4000             // KCONV * C_IN
#define NDIM    256              // 2 * C_OUT
#define COUT    128
#define VOCAB   257
#define VOCABP  256              // padding row of emb (zeros)

#define BMR     80               // m-rows per block (5 x 16)
#define NTILE   210              // ceil(MROWS/80): fits 256 CUs, no serial tail
#define SLABPF  40               // positions per full slab = 320 k = 10 BK32 iters
#define NSLABF  12               // full slabs; tail slab = 20 pos (5 kt)
#define NG      125              // total BK32 iterations
#define PLANE   (NDIM * 32)      // 8192 shorts per g-plane of Wtf
#define AROWSH  328              // padded shorts per A-slab row (320 + 8)
#define STAGEN  (BMR * SLABPF)   // 3200 gathers per full slab

// ---------------- ws layout (bytes) ----------------
#define WTF_OFF   0ull
#define WTF_BYTES ((size_t)NG * PLANE * 2)                  // 2,048,000
#define POOL_OFF  (WTF_OFF + WTF_BYTES)                     // 1024 floats
#define CNT_OFF   (POOL_OFF + 4096)                         // 1 int

typedef __attribute__((ext_vector_type(8))) __bf16 bf16x8;
typedef __attribute__((ext_vector_type(4))) float  floatx4;

__device__ inline unsigned short f2bf(float f) {
    union { float f; unsigned u; } c; c.f = f;
    return (unsigned short)((c.u + 0x7FFFu + ((c.u >> 16) & 1u)) >> 16);
}
__device__ inline unsigned pack2(float lo, float hi) {
    return (unsigned)f2bf(lo) | ((unsigned)f2bf(hi) << 16);
}

// barrier that waits ONLY for LDS ops — leaves global (B/x prefetch) loads in flight
#define LDS_BARRIER() asm volatile("s_waitcnt lgkmcnt(0)\n\ts_barrier" ::: "memory")

// ---------------- kernel 1: frag-major weights + zero pool/counter ----------------
// Wtf[g][n][kk] = w_n[e=(g*32+kk)&7][p=(g*32+kk)>>3]
__global__ __launch_bounds__(256) void wprep_kernel(const float* __restrict__ w1,
                                                    const float* __restrict__ w2,
                                                    unsigned short* __restrict__ Wtf,
                                                    float* __restrict__ pool,
                                                    int* __restrict__ cnt) {
    const int n   = blockIdx.x;                        // 0..255
    const int tid = threadIdx.x;
    __shared__ float tile[KDIM];                       // 16 KB
    const float* src = (n < COUT) ? (w1 + (size_t)n * KDIM)
                                  : (w2 + (size_t)(n - COUT) * KDIM);
    for (int i = tid; i < KDIM; i += 256) tile[i] = src[i];
    __syncthreads();
    for (int i = tid; i < KDIM; i += 256) {
        int g = i >> 5, kk = i & 31;
        Wtf[(size_t)g * PLANE + n * 32 + kk] = f2bf(tile[(i & 7) * KCONV + (i >> 3)]);
    }
    if (n == 0) {
        if (tid < 256) ((float4*)pool)[tid] = float4{0.f, 0.f, 0.f, 0.f}; // full 1024 floats
        if (tid == 0) *cnt = 0;
    }
}

// ---------------- kernel 2: fused embed + full-K GEMM + gate + max-pool + head ----------------
// BARRIER-PERIOD HALVING (round 6): SLABP 20 -> 40 (12 full slabs of 10 kt +
// one 20-pos tail slab of 5 kt) = 13 barrier periods instead of 25. Round-5
// showed the limiter is per-CU LDS-pipe time + per-slab fixed overhead
// (staging-burst lgkm drain, barrier skew, kt0 dependency stall ~2500 cyc per
// period); total LDS/MFMA/B work is invariant under slab size, so halving the
// period count removes ~12 periods of fixed overhead. As buffer 2x80x328
// shorts = 105KB (+4KB table) fits 160KB at our 1 block/CU (grid 210).
// Staging roles: 7 slots/thread (3200 gathers/slab); the 128-gather remainder
// (slot 6) is spread as 16 lanes x 8 waves so no single wave is skewed.
// Everything else identical to the verified r4 kernel:
// A: LDS emb-table gathers, slab double-buffered, compute-first ordering so
//    kt0's af waits cover only its own ds_reads and staging drains into the
//    lgkm-only barrier. B: frag-major Wtf, depth-2 register prefetch (never
//    drained by LDS_BARRIER). x prefetched a full slab ahead on vmcnt.
// HEAD FUSION: no cache-maintenance fences (atomicMax is device-scope on
// CDNA): vmcnt(0) drain -> __syncthreads -> RELAXED agent fetch_add; winner
// reads pool with per-access agent-scope loads.
__global__ __launch_bounds__(512) void gemm_kernel(const int* __restrict__ x,
                                                   const float* __restrict__ emb,
                                                   const unsigned short* __restrict__ Wtf,
                                                   const float* __restrict__ b1,
                                                   const float* __restrict__ b2,
                                                   float* __restrict__ pool,
                                                   int* __restrict__ cnt,
                                                   const float* __restrict__ wd1,
                                                   const float* __restrict__ bd1,
                                                   const float* __restrict__ wd2,
                                                   const float* __restrict__ bd2,
                                                   float* __restrict__ out) {
    __shared__ unsigned short tableL[VOCAB * 8];       // 4112 B
    __shared__ unsigned short As[2][BMR * AROWSH];     // 2 x 52.5 KB

    const int tid  = threadIdx.x;
    const int lane = tid & 63;
    const int wv   = tid >> 6;                         // 0..7
    const int m0   = blockIdx.x * BMR;
    const int r16  = lane & 15;
    const int q    = lane >> 4;                        // 0..3

    // ---- build bf16 emb table in LDS ----
    if (tid < VOCAB) {
        const float4* er = (const float4*)(emb + tid * 8);
        float4 a = er[0], b = er[1];
        uint4 u;
        u.x = pack2(a.x, a.y); u.y = pack2(a.z, a.w);
        u.z = pack2(b.x, b.y); u.w = pack2(b.z, b.w);
        *(uint4*)(tableL + tid * 8) = u;
    }

    // ---- staging roles: slots l=0..5: idx = tid + 512*l (all < 3200);
    //      slot 6: remainder 128 spread as lanes 0..15 of each wave ----
    const int* xptr[7];
    int        loff[7];
    bool       sval[7];
#pragma unroll
    for (int l = 0; l < 7; ++l) {
        int  idx = (l < 6) ? (tid + 512 * l)
                           : (6 * 512 + wv * 16 + (lane & 15));
        bool act = (l < 6) || (lane < 16);
        int row = idx / SLABPF;                        // < 80 for valid slots
        int pos = idx - row * SLABPF;                  // 0..39
        int am  = m0 + row;
        bool av = act && (am < MROWS) && (row < BMR);
        sval[l] = av;
        int amc = av ? am : 0;
        int b   = amc / TWIN;
        int t   = amc - b * TWIN;
        xptr[l] = x + ((size_t)b * LSEQ + (size_t)t * KCONV + pos);
        loff[l] = (av ? row : 0) * AROWSH + pos * 8;
    }

    // ---- compute role ----
    const int o = wv * 16 + r16;                       // 0..127
    const size_t boff0 = (size_t)o * 32 + q * 8;
    const size_t boff1 = (size_t)(o + 128) * 32 + q * 8;

    floatx4 acc[5][2];
#pragma unroll
    for (int i = 0; i < 5; ++i) { acc[i][0] = floatx4{0,0,0,0}; acc[i][1] = floatx4{0,0,0,0}; }

    // ---- x values for slab 0 ----
    int xv[7], xn[7];
#pragma unroll
    for (int l = 0; l < 7; ++l) xv[l] = sval[l] ? xptr[l][0] : VOCABP;
    __syncthreads();                                   // table visible

    // ---- stage slab 0 into buf 0 (unavoidably before first compute) ----
#pragma unroll
    for (int l = 0; l < 7; ++l) {
        if (l == 6 && lane >= 16) break;               // only lanes 0-15 in slot 6
        uint4 g = *(const uint4*)(tableL + xv[l] * 8);
        *(uint4*)((unsigned short*)As + loff[l]) = g;
    }
#pragma unroll
    for (int l = 0; l < 7; ++l) xv[l] = sval[l] ? xptr[l][SLABPF] : VOCABP;
    LDS_BARRIER();

    // ---- B prefetch prologue: g=0,1 ----
    bf16x8 bc0[2], bc1[2], bc2[2] = {};
    bc0[0] = *(const bf16x8*)(Wtf + boff0);
    bc0[1] = *(const bf16x8*)(Wtf + boff1);
    bc1[0] = *(const bf16x8*)(Wtf + PLANE + boff0);
    bc1[1] = *(const bf16x8*)(Wtf + PLANE + boff1);

    int buf = 0;
    for (int s = 0; s < NSLABF; ++s) {                 // 12 full slabs
        // issue x loads for slab s+2 early (vmcnt; a full slab of cover)
        if (s + 2 <= NSLABF) {                         // slab 12 = tail
#pragma unroll
            for (int l = 0; l < 7; ++l)
                xn[l] = sval[l] ? xptr[l][(s + 2) * SLABPF] : VOCABP;
        }

        // ---- 10 BK=32 iterations from As[buf]; B depth-2 register pipeline ----
        const unsigned short* Asb = (const unsigned short*)As + buf * (BMR * AROWSH);
#pragma unroll
        for (int kt = 0; kt < 10; ++kt) {
            const int g = s * 10 + kt;
            if (g + 2 < NG) {
                const unsigned short* Wp = Wtf + (size_t)(g + 2) * PLANE;
                bc2[0] = *(const bf16x8*)(Wp + boff0);
                bc2[1] = *(const bf16x8*)(Wp + boff1);
            }
            bf16x8 af[5];
#pragma unroll
            for (int i = 0; i < 5; ++i)
                af[i] = *(const bf16x8*)(Asb + (i * 16 + r16) * AROWSH + (kt * 4 + q) * 8);
#pragma unroll
            for (int i = 0; i < 5; ++i) {
                acc[i][0] = __builtin_amdgcn_mfma_f32_16x16x32_bf16(af[i], bc0[0], acc[i][0], 0, 0, 0);
                acc[i][1] = __builtin_amdgcn_mfma_f32_16x16x32_bf16(af[i], bc0[1], acc[i][1], 0, 0, 0);
            }
            bc0[0] = bc1[0]; bc0[1] = bc1[1];
            bc1[0] = bc2[0]; bc1[1] = bc2[1];
        }

        // ---- NOW stage slab s+1 into buf^1 (drains into the barrier) ----
        // (s+1 <= 12 always; slab 12 is the 20-pos tail: positions 20-39 of
        //  its As rows get garbage from x[480+pos] — in-bounds reads, never
        //  consumed by the 5-kt tail loop.)
        {
            unsigned short* d = (unsigned short*)As + (buf ^ 1) * (BMR * AROWSH);
#pragma unroll
            for (int l = 0; l < 7; ++l) {
                if (l == 6 && lane >= 16) break;
                uint4 g = *(const uint4*)(tableL + xv[l] * 8);
                *(uint4*)(d + loff[l]) = g;
            }
        }
#pragma unroll
        for (int l = 0; l < 7; ++l) xv[l] = xn[l];
        LDS_BARRIER();
        buf ^= 1;
    }

    // ---- tail slab (positions 480..499): 5 kt, no staging, no barrier ----
    {
        const unsigned short* Asb = (const unsigned short*)As + buf * (BMR * AROWSH);
#pragma unroll
        for (int kt = 0; kt < 5; ++kt) {
            const int g = NSLABF * 10 + kt;            // 120..124
            if (g + 2 < NG) {
                const unsigned short* Wp = Wtf + (size_t)(g + 2) * PLANE;
                bc2[0] = *(const bf16x8*)(Wp + boff0);
                bc2[1] = *(const bf16x8*)(Wp + boff1);
            }
            bf16x8 af[5];
#pragma unroll
            for (int i = 0; i < 5; ++i)
                af[i] = *(const bf16x8*)(Asb + (i * 16 + r16) * AROWSH + (kt * 4 + q) * 8);
#pragma unroll
            for (int i = 0; i < 5; ++i) {
                acc[i][0] = __builtin_amdgcn_mfma_f32_16x16x32_bf16(af[i], bc0[0], acc[i][0], 0, 0, 0);
                acc[i][1] = __builtin_amdgcn_mfma_f32_16x16x32_bf16(af[i], bc0[1], acc[i][1], 0, 0, 0);
            }
            bc0[0] = bc1[0]; bc0[1] = bc1[1];
            bc1[0] = bc2[0]; bc1[1] = bc2[1];
        }
    }

    // ---- epilogue: gate + per-batch max in registers, atomicMax flush ----
    // C/D layout: col = lane&15 (n), row = q*4 + reg (m).
    const float b1v = b1[o], b2v = b2[o];
    float cur = 0.0f;
    int curb  = (m0 + q * 4) / TWIN;
#pragma unroll
    for (int i = 0; i < 5; ++i) {
#pragma unroll
        for (int rg = 0; rg < 4; ++rg) {
            const int row = m0 + i * 16 + q * 4 + rg;
            if (row < MROWS) {
                const int bb = row / TWIN;
                if (bb != curb) {
                    atomicMax((int*)&pool[curb * COUT + o], __float_as_int(cur));
                    cur = 0.0f; curb = bb;
                }
                const float c1 = acc[i][0][rg] + b1v;
                const float c2 = acc[i][1][rg] + b2v;
                const float g  = fmaxf(c1, 0.0f) / (1.0f + __expf(-c2));
                cur = fmaxf(cur, g);
            }
        }
    }
    atomicMax((int*)&pool[curb * COUT + o], __float_as_int(cur));

    // ---- fused head: last block to finish does the dense layers ----
    // Drain this wave's device-scope atomics (completion at coherent point),
    // then barrier so ALL waves' atomics are drained, then relaxed counter.
    asm volatile("s_waitcnt vmcnt(0)" ::: "memory");
    __syncthreads();
    __shared__ int lastFlag;
    if (tid == 0) {
        int prev = __hip_atomic_fetch_add(cnt, 1, __ATOMIC_RELAXED, __HIP_MEMORY_SCOPE_AGENT);
        lastFlag = (prev == NTILE - 1) ? 1 : 0;
    }
    __syncthreads();
    if (!lastFlag) return;

    // reuse As as scratch: poolL[1024] + red[8][128]
    float* poolL = (float*)As;
    float* red   = poolL + BATCH * COUT;
    // agent-scope per-access loads: coherent view of the atomicMax results
    poolL[tid] = __int_as_float(
        __hip_atomic_load((int*)&pool[tid], __ATOMIC_RELAXED, __HIP_MEMORY_SCOPE_AGENT));
    poolL[tid + 512] = __int_as_float(
        __hip_atomic_load((int*)&pool[tid + 512], __ATOMIC_RELAXED, __HIP_MEMORY_SCOPE_AGENT));
    __syncthreads();

    if (tid < COUT) {
        const int j = tid;
        const float wj = wd2[j];
#pragma unroll
        for (int b = 0; b < BATCH; ++b) {
            float s = bd1[j];
            for (int i = 0; i < COUT; ++i) s += poolL[b * COUT + i] * wd1[j * COUT + i];
            red[b * COUT + j] = fmaxf(s, 0.0f) * wj;
        }
    }
    __syncthreads();
    if (tid < BATCH) {
        float s = 0.0f;
        for (int i = 0; i < COUT; ++i) s += red[tid * COUT + i];
        out[tid] = 1.0f / (1.0f + expf(-(s + bd2[0])));
    }
}

// ---------------- launch ----------------
extern "C" void kernel_launch(void* const* d_in, const int* in_sizes, int n_in,
                              void* d_out, int out_size, void* d_ws, size_t ws_size,
                              hipStream_t stream) {
    const int*   x   = (const int*)d_in[0];
    const float* emb = (const float*)d_in[1];
    const float* w1  = (const float*)d_in[2];
    const float* b1  = (const float*)d_in[3];
    const float* w2  = (const float*)d_in[4];
    const float* b2  = (const float*)d_in[5];
    const float* wd1 = (const float*)d_in[6];
    const float* bd1 = (const float*)d_in[7];
    const float* wd2 = (const float*)d_in[8];
    const float* bd2 = (const float*)d_in[9];
    float* out = (float*)d_out;

    unsigned short* Wtf  = (unsigned short*)((char*)d_ws + WTF_OFF);
    float*          pool = (float*)((char*)d_ws + POOL_OFF);
    int*            cnt  = (int*)((char*)d_ws + CNT_OFF);

    wprep_kernel<<<dim3(NDIM), dim3(256), 0, stream>>>(w1, w2, Wtf, pool, cnt);
    gemm_kernel<<<dim3(NTILE), dim3(512), 0, stream>>>(x, emb, Wtf, b1, b2, pool, cnt,
                                                       wd1, bd1, wd2, bd2, out);
}

// Round 7
// 161.059 us; speedup vs baseline: 1.3284x; 1.0537x over previous
//
#include <hip/hip_runtime.h>

// ---------------- problem constants ----------------
#define BATCH   8
#define LSEQ    1048576          // 1<<20
#define KCONV   500
#define TWIN    2097             // (L-K)/K + 1
#define MROWS   16776            // BATCH*TWIN
#define KDIM    4000             // KCONV * C_IN
#define NDIM    256              // 2 * C_OUT
#define COUT    128
#define VOCAB   257
#define VOCABP  256              // padding row of emb (zeros)

#define BMR     80               // m-rows per block (5 x 16)
#define NTILE   210              // ceil(MROWS/80): fits 256 CUs, no serial tail
#define SLABP   20               // positions per slab = 160 k = 5 BK32 iters
#define NSLAB   25
#define NG      125              // total BK32 iterations
#define PLANE   (NDIM * 32)      // 8192 shorts per g-plane of Wtf
#define AROWSH  168              // padded shorts per A-slab row (160 + 8)
#define STAGEN  (BMR * SLABP)    // 1600 gathers per slab
#define TSTRIDE 18               // shorts per emb-table entry (36B): entry-base bank
                                 // = (9*xv)%32, gcd(9,32)=1 -> full 32-bank spread
                                 // (16B stride had gcd(4,32)=4 -> 8 positions -> the
                                 // 5.25M measured gather conflicts)

// ---------------- ws layout (bytes) ----------------
#define WTF_OFF   0ull
#define WTF_BYTES ((size_t)NG * PLANE * 2)                  // 2,048,000
#define POOL_OFF  (WTF_OFF + WTF_BYTES)                     // 1024 floats
#define CNT_OFF   (POOL_OFF + 4096)                         // 1 int

typedef __attribute__((ext_vector_type(8))) __bf16 bf16x8;
typedef __attribute__((ext_vector_type(4))) float  floatx4;

__device__ inline unsigned short f2bf(float f) {
    union { float f; unsigned u; } c; c.f = f;
    return (unsigned short)((c.u + 0x7FFFu + ((c.u >> 16) & 1u)) >> 16);
}
__device__ inline unsigned pack2(float lo, float hi) {
    return (unsigned)f2bf(lo) | ((unsigned)f2bf(hi) << 16);
}

// barrier that waits ONLY for LDS ops — leaves global (B/x prefetch) loads in flight
#define LDS_BARRIER() asm volatile("s_waitcnt lgkmcnt(0)\n\ts_barrier" ::: "memory")

// ---------------- kernel 1: frag-major weights + zero pool/counter ----------------
// Wtf[g][n][kk] = w_n[e=(g*32+kk)&7][p=(g*32+kk)>>3]
__global__ __launch_bounds__(256) void wprep_kernel(const float* __restrict__ w1,
                                                    const float* __restrict__ w2,
                                                    unsigned short* __restrict__ Wtf,
                                                    float* __restrict__ pool,
                                                    int* __restrict__ cnt) {
    const int n   = blockIdx.x;                        // 0..255
    const int tid = threadIdx.x;
    __shared__ float tile[KDIM];                       // 16 KB
    const float* src = (n < COUT) ? (w1 + (size_t)n * KDIM)
                                  : (w2 + (size_t)(n - COUT) * KDIM);
    for (int i = tid; i < KDIM; i += 256) tile[i] = src[i];
    __syncthreads();
    for (int i = tid; i < KDIM; i += 256) {
        int g = i >> 5, kk = i & 31;
        Wtf[(size_t)g * PLANE + n * 32 + kk] = f2bf(tile[(i & 7) * KCONV + (i >> 3)]);
    }
    if (n == 0) {
        if (tid < 256) ((float4*)pool)[tid] = float4{0.f, 0.f, 0.f, 0.f}; // full 1024 floats
        if (tid == 0) *cnt = 0;
    }
}

// ---------------- kernel 2: fused embed + full-K GEMM + gate + max-pool + head ----------------
// ROUND 7 — in-period residue attack (r6 proved slab-count is not the cost):
// (a) CONFLICT-FREE TABLE: emb entries padded to 36B (TSTRIDE=18 shorts), so
//     64 random-lane gathers spread over all 32 banks (~2 req/bank = free per
//     m136) instead of 8 base positions (the 5.25M conflict cycles).
// (b) STAGGERED STAGING: the old end-of-slab burst had all 8 symmetric waves
//     doing 1600 gathers+writes with the MFMA pipe idle (~2000 cy/slab).
//     Now: gather-READ for slot l issues at kt=l (before that kt's MFMAs —
//     latency hidden under them; compiler's counted lgkm wait for af leaves
//     the gather outstanding); gather-WRITE for slot l issues at kt=l+1
//     (data arrived a whole kt ago -> no stall; lgkm is in-order so the next
//     af wait drains it for free). Staging LDS work now runs under the MFMA
//     region's LDS slack; only the final write precedes the barrier.
// Everything else is the verified r4 structure: SLABP=20 double-buffered As,
// compute-first ordering, frag-major Wtf with depth-2 register B prefetch
// (never drained by the lgkm-only LDS_BARRIER), x prefetched a slab ahead,
// fused head with relaxed device-scope sync (no cache-maintenance fences).
__global__ __launch_bounds__(512) void gemm_kernel(const int* __restrict__ x,
                                                   const float* __restrict__ emb,
                                                   const unsigned short* __restrict__ Wtf,
                                                   const float* __restrict__ b1,
                                                   const float* __restrict__ b2,
                                                   float* __restrict__ pool,
                                                   int* __restrict__ cnt,
                                                   const float* __restrict__ wd1,
                                                   const float* __restrict__ bd1,
                                                   const float* __restrict__ wd2,
                                                   const float* __restrict__ bd2,
                                                   float* __restrict__ out) {
    __shared__ __align__(16) unsigned short tableL[VOCAB * TSTRIDE]; // 9252 B
    __shared__ __align__(16) unsigned short As[2][BMR * AROWSH];     // 2 x 26.25 KB

    const int tid  = threadIdx.x;
    const int lane = tid & 63;
    const int wv   = tid >> 6;                         // 0..7
    const int m0   = blockIdx.x * BMR;
    const int r16  = lane & 15;
    const int q    = lane >> 4;                        // 0..3

    // ---- build bf16 emb table in LDS (36B stride; 4 dword stores, 4B-aligned) ----
    if (tid < VOCAB) {
        const float4* er = (const float4*)(emb + tid * 8);
        float4 a = er[0], b = er[1];
        unsigned* tb = (unsigned*)(tableL + tid * TSTRIDE);
        tb[0] = pack2(a.x, a.y); tb[1] = pack2(a.z, a.w);
        tb[2] = pack2(b.x, b.y); tb[3] = pack2(b.z, b.w);
    }

    // ---- staging roles: thread handles idx = tid + 512*l (idx < 1600) ----
    const int* xptr[4];
    int        loff[4];
    bool       sval[4];
    bool       sact[4];
#pragma unroll
    for (int l = 0; l < 4; ++l) {
        sact[l] = (l < 3) || (tid < STAGEN - 3 * 512);  // slot 3: tids 0..63 only
        int idx = tid + 512 * l;
        sval[l] = (idx < STAGEN);
        int ic  = sval[l] ? idx : 0;
        int row = ic / SLABP;
        int pos = ic - row * SLABP;
        int am  = m0 + row;
        bool av = sval[l] && (am < MROWS);
        sval[l] = av;
        int amc = av ? am : 0;
        int b   = amc / TWIN;
        int t   = amc - b * TWIN;
        xptr[l] = x + ((size_t)b * LSEQ + (size_t)t * KCONV + pos);
        loff[l] = row * AROWSH + pos * 8;
    }

    // ---- compute role ----
    const int o = wv * 16 + r16;                       // 0..127
    const size_t boff0 = (size_t)o * 32 + q * 8;
    const size_t boff1 = (size_t)(o + 128) * 32 + q * 8;

    floatx4 acc[5][2];
#pragma unroll
    for (int i = 0; i < 5; ++i) { acc[i][0] = floatx4{0,0,0,0}; acc[i][1] = floatx4{0,0,0,0}; }

    // ---- x values for slab 0 ----
    int xv[4], xn[4];
#pragma unroll
    for (int l = 0; l < 4; ++l) xv[l] = sval[l] ? xptr[l][0] : VOCABP;
    __syncthreads();                                   // table visible

    // ---- stage slab 0 into buf 0 (unavoidable burst before first compute) ----
#pragma unroll
    for (int l = 0; l < 4; ++l) {
        if (sact[l]) {
            const unsigned* gb = (const unsigned*)(tableL + xv[l] * TSTRIDE);
            uint4 g; g.x = gb[0]; g.y = gb[1]; g.z = gb[2]; g.w = gb[3];
            *(uint4*)((unsigned short*)As + loff[l]) = g;
        }
    }
#pragma unroll
    for (int l = 0; l < 4; ++l) xv[l] = sval[l] ? xptr[l][SLABP] : VOCABP;
    LDS_BARRIER();

    // ---- B prefetch prologue: g=0,1 ----
    bf16x8 bc0[2], bc1[2], bc2[2] = {};
    bc0[0] = *(const bf16x8*)(Wtf + boff0);
    bc0[1] = *(const bf16x8*)(Wtf + boff1);
    bc1[0] = *(const bf16x8*)(Wtf + PLANE + boff0);
    bc1[1] = *(const bf16x8*)(Wtf + PLANE + boff1);

    int buf = 0;
    for (int s = 0; s < NSLAB; ++s) {
        // issue x loads for slab s+2 early (vmcnt; a full slab of cover)
        if (s + 2 < NSLAB) {
#pragma unroll
            for (int l = 0; l < 4; ++l)
                xn[l] = sval[l] ? xptr[l][(s + 2) * SLABP] : VOCABP;
        }

        const unsigned short* Asb  = (const unsigned short*)As + buf * (BMR * AROWSH);
        unsigned short*       dstS = (unsigned short*)As + (buf ^ 1) * (BMR * AROWSH);
        const bool stg = (s + 1 < NSLAB);
        uint4 gr[4];

        // ---- 5 BK=32 iterations; B depth-2 register pipeline; staged gathers ----
#pragma unroll
        for (int kt = 0; kt < 5; ++kt) {
            const int g = s * 5 + kt;
            if (g + 2 < NG) {
                const unsigned short* Wp = Wtf + (size_t)(g + 2) * PLANE;
                bc2[0] = *(const bf16x8*)(Wp + boff0);
                bc2[1] = *(const bf16x8*)(Wp + boff1);
            }
            bf16x8 af[5];
#pragma unroll
            for (int i = 0; i < 5; ++i)
                af[i] = *(const bf16x8*)(Asb + (i * 16 + r16) * AROWSH + (kt * 4 + q) * 8);

            // gather-READ slot kt: issued with this kt's af reads; the MFMA's
            // counted lgkm wait only needs af, leaving these outstanding.
            if (kt < 4 && stg && sact[kt]) {
                const unsigned* gb = (const unsigned*)(tableL + xv[kt] * TSTRIDE);
                gr[kt].x = gb[0]; gr[kt].y = gb[1]; gr[kt].z = gb[2]; gr[kt].w = gb[3];
            }

#pragma unroll
            for (int i = 0; i < 5; ++i) {
                acc[i][0] = __builtin_amdgcn_mfma_f32_16x16x32_bf16(af[i], bc0[0], acc[i][0], 0, 0, 0);
                acc[i][1] = __builtin_amdgcn_mfma_f32_16x16x32_bf16(af[i], bc0[1], acc[i][1], 0, 0, 0);
            }
            bc0[0] = bc1[0]; bc0[1] = bc1[1];
            bc1[0] = bc2[0]; bc1[1] = bc2[1];

            // gather-WRITE slot kt-1: data arrived a full kt ago -> no stall;
            // kt's in-order lgkm traffic already drained the read.
            if (kt >= 1 && stg && sact[kt - 1])
                *(uint4*)(dstS + loff[kt - 1]) = gr[kt - 1];
        }
        // slot 3 written inside the loop at kt=4 — nothing left but the barrier.
#pragma unroll
        for (int l = 0; l < 4; ++l) xv[l] = xn[l];
        LDS_BARRIER();
        buf ^= 1;
    }

    // ---- epilogue: gate + per-batch max in registers, atomicMax flush ----
    // C/D layout: col = lane&15 (n), row = q*4 + reg (m).
    const float b1v = b1[o], b2v = b2[o];
    float cur = 0.0f;
    int curb  = (m0 + q * 4) / TWIN;
#pragma unroll
    for (int i = 0; i < 5; ++i) {
#pragma unroll
        for (int rg = 0; rg < 4; ++rg) {
            const int row = m0 + i * 16 + q * 4 + rg;
            if (row < MROWS) {
                const int bb = row / TWIN;
                if (bb != curb) {
                    atomicMax((int*)&pool[curb * COUT + o], __float_as_int(cur));
                    cur = 0.0f; curb = bb;
                }
                const float c1 = acc[i][0][rg] + b1v;
                const float c2 = acc[i][1][rg] + b2v;
                const float g  = fmaxf(c1, 0.0f) / (1.0f + __expf(-c2));
                cur = fmaxf(cur, g);
            }
        }
    }
    atomicMax((int*)&pool[curb * COUT + o], __float_as_int(cur));

    // ---- fused head: last block to finish does the dense layers ----
    // Drain this wave's device-scope atomics, barrier so all waves' atomics
    // are complete, then relaxed counter (no cache-maintenance fences — the
    // r3 ACQ_REL/threadfence variant cost ~45us in L2 writebacks).
    asm volatile("s_waitcnt vmcnt(0)" ::: "memory");
    __syncthreads();
    __shared__ int lastFlag;
    if (tid == 0) {
        int prev = __hip_atomic_fetch_add(cnt, 1, __ATOMIC_RELAXED, __HIP_MEMORY_SCOPE_AGENT);
        lastFlag = (prev == NTILE - 1) ? 1 : 0;
    }
    __syncthreads();
    if (!lastFlag) return;

    // reuse As as scratch: poolL[1024] + red[8][128]
    float* poolL = (float*)As;
    float* red   = poolL + BATCH * COUT;
    // agent-scope per-access loads: coherent view of the atomicMax results
    poolL[tid] = __int_as_float(
        __hip_atomic_load((int*)&pool[tid], __ATOMIC_RELAXED, __HIP_MEMORY_SCOPE_AGENT));
    poolL[tid + 512] = __int_as_float(
        __hip_atomic_load((int*)&pool[tid + 512], __ATOMIC_RELAXED, __HIP_MEMORY_SCOPE_AGENT));
    __syncthreads();

    if (tid < COUT) {
        const int j = tid;
        const float wj = wd2[j];
#pragma unroll
        for (int b = 0; b < BATCH; ++b) {
            float s = bd1[j];
            for (int i = 0; i < COUT; ++i) s += poolL[b * COUT + i] * wd1[j * COUT + i];
            red[b * COUT + j] = fmaxf(s, 0.0f) * wj;
        }
    }
    __syncthreads();
    if (tid < BATCH) {
        float s = 0.0f;
        for (int i = 0; i < COUT; ++i) s += red[tid * COUT + i];
        out[tid] = 1.0f / (1.0f + expf(-(s + bd2[0])));
    }
}

// ---------------- launch ----------------
extern "C" void kernel_launch(void* const* d_in, const int* in_sizes, int n_in,
                              void* d_out, int out_size, void* d_ws, size_t ws_size,
                              hipStream_t stream) {
    const int*   x   = (const int*)d_in[0];
    const float* emb = (const float*)d_in[1];
    const float* w1  = (const float*)d_in[2];
    const float* b1  = (const float*)d_in[3];
    const float* w2  = (const float*)d_in[4];
    const float* b2  = (const float*)d_in[5];
    const float* wd1 = (const float*)d_in[6];
    const float* bd1 = (const float*)d_in[7];
    const float* wd2 = (const float*)d_in[8];
    const float* bd2 = (const float*)d_in[9];
    float* out = (float*)d_out;

    unsigned short* Wtf  = (unsigned short*)((char*)d_ws + WTF_OFF);
    float*          pool = (float*)((char*)d_ws + POOL_OFF);
    int*            cnt  = (int*)((char*)d_ws + CNT_OFF);

    wprep_kernel<<<dim3(NDIM), dim3(256), 0, stream>>>(w1, w2, Wtf, pool, cnt);
    gemm_kernel<<<dim3(NTILE), dim3(512), 0, stream>>>(x, emb, Wtf, b1, b2, pool, cnt,
                                                       wd1, bd1, wd2, bd2, out);
}